// Round 1
// 347.820 us; speedup vs baseline: 1.1139x; 1.1139x over previous
//
#include <hip/hip_runtime.h>
#include <hip/hip_bf16.h>

#define NN 100000
#define NE 1600000
#define NEG_SLOPE 0.2f
#define GEPS 1e-16f
#define WSHIFT 4.0f   // global exp shift: w = exp(alpha-4), softmax-invariant, keeps f16 in range

// ---- atomic-free CSR-build geometry ----
#define HB 32              // edge chunks (deterministic: chunk = e / EB)
#define EB (NE / HB)       // 50000 edges per chunk (multiple of 4)
#define HPASS 4            // node-range passes per chunk
#define HBIN 25000         // bins per pass (4*25000 = NN exactly)
#define HBW (HBIN / 2)     // packed 2x16-bit counters per LDS word -> 50 KB LDS

typedef __attribute__((ext_vector_type(8))) short short8;
typedef __attribute__((ext_vector_type(4))) float f32x4;
typedef __attribute__((ext_vector_type(2))) _Float16 h2v;

// fp32 -> bf16 round-to-nearest-even (MFMA staging only)
__device__ __forceinline__ unsigned short f2b(float f) {
  unsigned u = __float_as_uint(f);
  u += 0x7fffu + ((u >> 16) & 1u);
  return (unsigned short)(u >> 16);
}
// fp32 -> f16 (h1 storage: f16 has 11-bit mantissa, better than bf16 for |h|<8)
__device__ __forceinline__ unsigned short f2h(float f) {
  _Float16 h = (_Float16)f;
  return __builtin_bit_cast(unsigned short, h);
}
// pack two fp32 into f16x2 (lo, hi)
__device__ __forceinline__ unsigned pkh2(float lo, float hi) {
  return (unsigned)f2h(lo) | ((unsigned)f2h(hi) << 16);
}
__device__ __forceinline__ float dot2h(unsigned a, unsigned b, float c) {
  return __builtin_amdgcn_fdot2(__builtin_bit_cast(h2v, a), __builtin_bit_cast(h2v, b), c, false);
}
__device__ __forceinline__ unsigned permb(unsigned s0, unsigned s1, int sel) {
  return __builtin_amdgcn_perm(s0, s1, sel);
}
#define HSEL_LO 0x05040100   // (s1.lo16, s0.lo16)
#define HSEL_HI 0x07060302   // (s1.hi16, s0.hi16)
#define ONE2    0x3C003C00u  // f16 (1.0, 1.0)

// ---------- prep: q (edge-att vectors) + pq[k] = (W1@as1, W1@ad1) per head ----------
__global__ void k_prep(const float* __restrict__ We1, const float* __restrict__ ae1,
                       const float* __restrict__ We2, const float* __restrict__ ae2,
                       const float* __restrict__ W1, const float* __restrict__ as1,
                       const float* __restrict__ ad1,
                       float* __restrict__ q, float4* __restrict__ pq) {
  int t = threadIdx.x;
  if (t < 6) {
    int d = t >> 1, hh = t & 1;
    float s = 0.f;
    for (int c = 0; c < 64; ++c) s += We1[d * 128 + hh * 64 + c] * ae1[hh * 64 + c];
    q[t] = s;
  } else if (t < 9) {
    int d = t - 6;
    q[8 + d] = We2[d * 2 + 0] * ae2[0] + We2[d * 2 + 1] * ae2[1];
  }
  if (t < 128) {
    float s0 = 0.f, s1 = 0.f, d0 = 0.f, d1 = 0.f;
    for (int c = 0; c < 64; ++c) {
      float w0 = W1[t * 128 + c], w1 = W1[t * 128 + 64 + c];
      s0 += w0 * as1[c];      s1 += w1 * as1[64 + c];
      d0 += w0 * ad1[c];      d1 += w1 * ad1[64 + c];
    }
    pq[t] = make_float4(s0, s1, d0, d1);
  }
}

// ---------- layer1 GEMM via bf16 MFMA + fused attn scalars from fp32 x ----------
// Output h1b stored as f16 (not bf16): same MFMA, more precise storage.
__global__ __launch_bounds__(512, 4) void k_gemm(const float* __restrict__ x,
                                                 const float* __restrict__ W,
                                                 const float4* __restrict__ pq,
                                                 unsigned short* __restrict__ h1b,
                                                 float* __restrict__ a1s,
                                                 float* __restrict__ a1d) {
  __shared__ unsigned short xa[128 * 128];
  __shared__ unsigned short wt[128 * 128];
  int t = threadIdx.x;
  int row0 = blockIdx.x * 128;

  // stage W^T (fp32 -> bf16, transposed, swizzled)
  {
    int kr = t >> 2, n0 = (t & 3) * 32;
    const float* wp = &W[kr * 128 + n0];
    int cb = kr >> 3, klo = kr & 7;
#pragma unroll
    for (int j = 0; j < 8; ++j) {
      float4 v = *(const float4*)&wp[j * 4];
      int n = n0 + j * 4;
      wt[(n + 0) * 128 + ((cb ^ ((n + 0) & 15)) * 8) + klo] = f2b(v.x);
      wt[(n + 1) * 128 + ((cb ^ ((n + 1) & 15)) * 8) + klo] = f2b(v.y);
      wt[(n + 2) * 128 + ((cb ^ ((n + 2) & 15)) * 8) + klo] = f2b(v.z);
      wt[(n + 3) * 128 + ((cb ^ ((n + 3) & 15)) * 8) + klo] = f2b(v.w);
    }
  }
  // stage x tile (fp32 -> bf16, swizzled) + alpha-scalar partial dots on fp32 x
  {
    int lrow = t >> 2, qq = t & 3;
    int grow = row0 + lrow; if (grow >= NN) grow = NN - 1;
    const float* xp = &x[(size_t)grow * 128 + qq * 32];
    const float4* pqp = &pq[qq * 32];
    float ps0 = 0.f, ps1 = 0.f, pd0 = 0.f, pd1 = 0.f;
    int sw = lrow & 15;
#pragma unroll
    for (int j = 0; j < 4; ++j) {
      float4 u = *(const float4*)&xp[j * 8];
      float4 v = *(const float4*)&xp[j * 8 + 4];
      float xs[8] = {u.x, u.y, u.z, u.w, v.x, v.y, v.z, v.w};
      short8 sv;
#pragma unroll
      for (int e = 0; e < 8; ++e) {
        float4 pv = pqp[j * 8 + e];
        ps0 += xs[e] * pv.x; ps1 += xs[e] * pv.y;
        pd0 += xs[e] * pv.z; pd1 += xs[e] * pv.w;
        sv[e] = (short)f2b(xs[e]);
      }
      int c = qq * 4 + j;
      *(short8*)&xa[lrow * 128 + ((c ^ sw) * 8)] = sv;
    }
    ps0 += __shfl_xor(ps0, 1); ps0 += __shfl_xor(ps0, 2);
    ps1 += __shfl_xor(ps1, 1); ps1 += __shfl_xor(ps1, 2);
    pd0 += __shfl_xor(pd0, 1); pd0 += __shfl_xor(pd0, 2);
    pd1 += __shfl_xor(pd1, 1); pd1 += __shfl_xor(pd1, 2);
    if (qq == 0) {
      *(float2*)&a1s[grow * 2] = make_float2(ps0, ps1);
      *(float2*)&a1d[grow * 2] = make_float2(pd0, pd1);
    }
  }
  __syncthreads();

  int lane = t & 63, w = t >> 6;
  int m = lane & 15, quad = lane >> 4;
  int wm = (w & 1) * 64, wn = (w >> 1) * 32;
  f32x4 acc[4][2];
#pragma unroll
  for (int mi = 0; mi < 4; ++mi)
#pragma unroll
    for (int ni = 0; ni < 2; ++ni) acc[mi][ni] = (f32x4)(0.f);

#pragma unroll
  for (int kk = 0; kk < 4; ++kk) {
    int c = kk * 4 + quad;
    int co = (c ^ m) * 8;
    short8 a[4], b[2];
#pragma unroll
    for (int mi = 0; mi < 4; ++mi)
      a[mi] = *(const short8*)&xa[(wm + mi * 16 + m) * 128 + co];
#pragma unroll
    for (int ni = 0; ni < 2; ++ni)
      b[ni] = *(const short8*)&wt[(wn + ni * 16 + m) * 128 + co];
#pragma unroll
    for (int mi = 0; mi < 4; ++mi)
#pragma unroll
      for (int ni = 0; ni < 2; ++ni)
        acc[mi][ni] = __builtin_amdgcn_mfma_f32_16x16x32_bf16(a[mi], b[ni], acc[mi][ni], 0, 0, 0);
  }
#pragma unroll
  for (int mi = 0; mi < 4; ++mi)
#pragma unroll
    for (int r = 0; r < 4; ++r) {
      int grow = row0 + wm + mi * 16 + quad * 4 + r;
      if (grow >= NN) grow = NN - 1;
#pragma unroll
      for (int ni = 0; ni < 2; ++ni)
        h1b[(size_t)grow * 128 + wn + ni * 16 + m] = f2h(acc[mi][ni][r]);
    }
}

// ---------- CSR build: NO global atomics ----------
// Edges are split into HB=32 deterministic chunks (chunk = e/EB). Each block handles
// one (chunk, node-range-pass) pair: LDS histogram (2x16-bit counts packed per word),
// local rank from the LDS atomic return, partial per-chunk degree table written
// non-atomically. Worst-case per-chunk per-node count = EB = 50000 < 2^16 -> no carry.
__global__ __launch_bounds__(1024) void k_hist(const int* __restrict__ ei,
                                               unsigned short* __restrict__ off16,
                                               unsigned short* __restrict__ rank) {
  __shared__ unsigned cnt[HBW];          // 50 KB
  int b = blockIdx.x >> 2;               // edge chunk
  int pass = blockIdx.x & 3;             // node range
  int base = pass * HBIN;
  int t = threadIdx.x;
  for (int i = t; i < HBW; i += 1024) cnt[i] = 0;
  __syncthreads();
  const int* dsts = &ei[NE + b * EB];
  for (int i = t * 4; i < EB; i += 4096) {
    int4 d = *(const int4*)&dsts[i];
    int dv[4] = {d.x, d.y, d.z, d.w};
#pragma unroll
    for (int j = 0; j < 4; ++j) {
      int rel = dv[j] - base;
      if ((unsigned)rel < (unsigned)HBIN) {
        unsigned sh = (unsigned)(rel & 1) << 4;
        unsigned old = atomicAdd(&cnt[rel >> 1], 1u << sh);
        rank[b * EB + i + j] = (unsigned short)((old >> sh) & 0xffffu);
      }
    }
  }
  __syncthreads();
  // dump partial histogram: word i = counts for nodes (base+2i, base+2i+1)
  unsigned short* dp = &off16[(size_t)b * NN + base];
  for (int i = t; i < HBW; i += 1024) *(unsigned*)&dp[i * 2] = cnt[i];
}

// per-node total degree + in-place exclusive prefix over the HB chunk partials
__global__ void k_sumdeg(unsigned short* __restrict__ off16, int* __restrict__ deg) {
  int n = blockIdx.x * 256 + threadIdx.x;
  if (n >= NN) return;
  int run = 0;
#pragma unroll
  for (int b = 0; b < HB; ++b) {
    size_t idx = (size_t)b * NN + n;
    int c = off16[idx];
    off16[idx] = (unsigned short)run;   // exclusive offset of chunk b within node n
    run += c;
  }
  deg[n] = run;
}

// padded segment length: (deg+1) rounded up to multiple of 8
__device__ __forceinline__ int padlen(int d) { return (d + 8) & ~7; }

__global__ void k_scan1(const int* __restrict__ deg, int* __restrict__ bsum) {
  __shared__ int lds[256];
  int t = threadIdx.x;
  int base = blockIdx.x * 1024 + t * 4;
  int s = 0;
  for (int j = 0; j < 4; ++j) { int i = base + j; s += (i < NN) ? padlen(deg[i]) : 0; }
  lds[t] = s; __syncthreads();
  for (int o = 128; o > 0; o >>= 1) { if (t < o) lds[t] += lds[t + o]; __syncthreads(); }
  if (t == 0) bsum[blockIdx.x] = lds[0];
}

__global__ void k_scan2(int* __restrict__ bsum, int nb) {
  __shared__ int lds[128];
  int t = threadIdx.x;
  int v = (t < nb) ? bsum[t] : 0;
  lds[t] = v; __syncthreads();
  for (int o = 1; o < 128; o <<= 1) {
    int u = (t >= o) ? lds[t - o] : 0;
    __syncthreads();
    lds[t] += u;
    __syncthreads();
  }
  if (t < nb) bsum[t] = lds[t] - v;   // exclusive
}

// scan3: rowptr (padded), self-loop packet at slot 0, zero-weight pad packets at tail.
// Packet layout: .x = f16x2 (w0,w1) = exp(alpha-4), .y = ez, .z = src, .w = 0.
// Pad packet: w01 = 0 (agg1 adds zero), ez = -1e30 -> agg2 exp = 0.
__global__ void k_scan3(const int* __restrict__ deg, const int* __restrict__ bbase,
                        const float* __restrict__ a1s, const float* __restrict__ a1d,
                        int* __restrict__ rowptr, float4* __restrict__ cpk) {
  __shared__ int lds[256];
  int t = threadIdx.x;
  int base = blockIdx.x * 1024 + t * 4;
  int v[4]; int s = 0;
  for (int j = 0; j < 4; ++j) { int i = base + j; v[j] = (i < NN) ? padlen(deg[i]) : 0; s += v[j]; }
  lds[t] = s; __syncthreads();
  for (int o = 1; o < 256; o <<= 1) {
    int u = (t >= o) ? lds[t - o] : 0;
    __syncthreads();
    lds[t] += u;
    __syncthreads();
  }
  int excl = lds[t] - s + bbase[blockIdx.x];
  for (int j = 0; j < 4; ++j) {
    int i = base + j;
    if (i <= NN) rowptr[i] = excl;
    if (i < NN) {
      float al0 = a1s[i * 2] + a1d[i * 2];
      float al1 = a1s[i * 2 + 1] + a1d[i * 2 + 1];
      al0 = al0 > 0.f ? al0 : NEG_SLOPE * al0;
      al1 = al1 > 0.f ? al1 : NEG_SLOPE * al1;
      float4 pk;
      pk.x = __uint_as_float(pkh2(__expf(al0 - WSHIFT), __expf(al1 - WSHIFT)));
      pk.y = 0.f; pk.z = __int_as_float(i); pk.w = 0.f;
      cpk[excl] = pk;                       // self-loop at slot 0
      float4 pad;
      pad.x = 0.f; pad.y = -1e30f; pad.z = __int_as_float(i); pad.w = 0.f;
      for (int k = 1 + deg[i]; k < v[j]; ++k) cpk[excl + k] = pad;
    }
    excl += v[j];
  }
}

// ---------- scatter edges into CSR: NO atomics ----------
// pos = rowptr[dst] + 1 + off16[chunk][dst] + localrank   (chunk = e/EB, reproducible)
__global__ void k_scatter(const int* __restrict__ ei, const float* __restrict__ ef,
                          const float* __restrict__ a1s, const float* __restrict__ a1d,
                          const float* __restrict__ q, const int* __restrict__ rowptr,
                          const unsigned short* __restrict__ rank,
                          const unsigned short* __restrict__ off16,
                          float4* __restrict__ cpk) {
  int t4 = blockIdx.x * 256 + threadIdx.x;
  if (t4 >= NE / 4) return;
  int e0 = t4 * 4;
  int hb = e0 / EB;                       // all 4 edges in same chunk (EB % 4 == 0)
  const unsigned short* offp = &off16[(size_t)hb * NN];
  int4 ss = *(const int4*)&ei[e0];
  int4 dd = *(const int4*)&ei[NE + e0];
  ushort4 rk = *(const ushort4*)&rank[e0];
  float4 fA = *(const float4*)&ef[e0 * 3];
  float4 fB = *(const float4*)&ef[e0 * 3 + 4];
  float4 fC = *(const float4*)&ef[e0 * 3 + 8];
  float f[4][3] = {{fA.x, fA.y, fA.z}, {fA.w, fB.x, fB.y},
                   {fB.z, fB.w, fC.x}, {fC.y, fC.z, fC.w}};
  int src[4] = {ss.x, ss.y, ss.z, ss.w};
  int dst[4] = {dd.x, dd.y, dd.z, dd.w};
  int rnk[4] = {rk.x, rk.y, rk.z, rk.w};
#pragma unroll
  for (int j = 0; j < 4; ++j) {
    float e0h = f[j][0] * q[0] + f[j][1] * q[2] + f[j][2] * q[4];
    float e1h = f[j][0] * q[1] + f[j][1] * q[3] + f[j][2] * q[5];
    float ez  = f[j][0] * q[8] + f[j][1] * q[9] + f[j][2] * q[10];
    float al0 = a1s[src[j] * 2] + a1d[dst[j] * 2] + e0h;
    float al1 = a1s[src[j] * 2 + 1] + a1d[dst[j] * 2 + 1] + e1h;
    al0 = al0 > 0.f ? al0 : NEG_SLOPE * al0;
    al1 = al1 > 0.f ? al1 : NEG_SLOPE * al1;
    int pos = rowptr[dst[j]] + 1 + (int)offp[dst[j]] + rnk[j];
    float4 pk;
    pk.x = __uint_as_float(pkh2(__expf(al0 - WSHIFT), __expf(al1 - WSHIFT)));
    pk.y = ez; pk.z = __int_as_float(src[j]); pk.w = 0.f;
    cpk[pos] = pk;
  }
}

// ---------- layer1 aggregation + bias + ELU + layer2 projection epilogue ----------
// one wave per dst node; 16-lane granules; f16 h1 rows + f16x2 packed weights.
// Inner accumulation via v_perm channel-pairing + v_dot2_f32_f16 over edge pairs:
// 1 instr per (channel, edge-pair) instead of unpack+fma per (channel, edge).
__global__ __launch_bounds__(256) void k_agg1(const unsigned short* __restrict__ h1b,
                                              const int* __restrict__ rowptr,
                                              const float4* __restrict__ cpk,
                                              const float* __restrict__ b1,
                                              const float* __restrict__ W2,
                                              const float* __restrict__ as2,
                                              const float* __restrict__ ad2,
                                              float4* __restrict__ nd) {
  int n = (int)((blockIdx.x * 256 + threadIdx.x) >> 6);
  int lane = threadIdx.x & 63;
  if (n >= NN) return;
  int s0 = rowptr[n], s1 = rowptr[n + 1];
  int g = lane >> 4;
  int lp = lane & 15;
  int wsel = (lp >= 8) ? HSEL_HI : HSEL_LO;   // head select folded into weight perm

  float acc[8];
#pragma unroll
  for (int j = 0; j < 8; ++j) acc[j] = 0.f;
  float den = 0.f;

  int i = s0;
  for (; i + 16 <= s1; i += 16) {
    float4 pA = cpk[i + g], pB = cpk[i + 4 + g], pC = cpk[i + 8 + g], pD = cpk[i + 12 + g];
    uint4 vA = *((const uint4*)(h1b + ((size_t)__float_as_int(pA.z) << 7)) + lp);
    uint4 vB = *((const uint4*)(h1b + ((size_t)__float_as_int(pB.z) << 7)) + lp);
    uint4 vC = *((const uint4*)(h1b + ((size_t)__float_as_int(pC.z) << 7)) + lp);
    uint4 vD = *((const uint4*)(h1b + ((size_t)__float_as_int(pD.z) << 7)) + lp);
    unsigned wAB = permb(__float_as_uint(pB.x), __float_as_uint(pA.x), wsel);
    unsigned wCD = permb(__float_as_uint(pD.x), __float_as_uint(pC.x), wsel);
    den = dot2h(wAB, ONE2, den);
    den = dot2h(wCD, ONE2, den);
    acc[0] = dot2h(permb(vB.x, vA.x, HSEL_LO), wAB, acc[0]);
    acc[1] = dot2h(permb(vB.x, vA.x, HSEL_HI), wAB, acc[1]);
    acc[2] = dot2h(permb(vB.y, vA.y, HSEL_LO), wAB, acc[2]);
    acc[3] = dot2h(permb(vB.y, vA.y, HSEL_HI), wAB, acc[3]);
    acc[4] = dot2h(permb(vB.z, vA.z, HSEL_LO), wAB, acc[4]);
    acc[5] = dot2h(permb(vB.z, vA.z, HSEL_HI), wAB, acc[5]);
    acc[6] = dot2h(permb(vB.w, vA.w, HSEL_LO), wAB, acc[6]);
    acc[7] = dot2h(permb(vB.w, vA.w, HSEL_HI), wAB, acc[7]);
    acc[0] = dot2h(permb(vD.x, vC.x, HSEL_LO), wCD, acc[0]);
    acc[1] = dot2h(permb(vD.x, vC.x, HSEL_HI), wCD, acc[1]);
    acc[2] = dot2h(permb(vD.y, vC.y, HSEL_LO), wCD, acc[2]);
    acc[3] = dot2h(permb(vD.y, vC.y, HSEL_HI), wCD, acc[3]);
    acc[4] = dot2h(permb(vD.z, vC.z, HSEL_LO), wCD, acc[4]);
    acc[5] = dot2h(permb(vD.z, vC.z, HSEL_HI), wCD, acc[5]);
    acc[6] = dot2h(permb(vD.w, vC.w, HSEL_LO), wCD, acc[6]);
    acc[7] = dot2h(permb(vD.w, vC.w, HSEL_HI), wCD, acc[7]);
  }
  if (i < s1) {                       // exactly one 8-edge block
    float4 pA = cpk[i + g], pB = cpk[i + 4 + g];
    uint4 vA = *((const uint4*)(h1b + ((size_t)__float_as_int(pA.z) << 7)) + lp);
    uint4 vB = *((const uint4*)(h1b + ((size_t)__float_as_int(pB.z) << 7)) + lp);
    unsigned wAB = permb(__float_as_uint(pB.x), __float_as_uint(pA.x), wsel);
    den = dot2h(wAB, ONE2, den);
    acc[0] = dot2h(permb(vB.x, vA.x, HSEL_LO), wAB, acc[0]);
    acc[1] = dot2h(permb(vB.x, vA.x, HSEL_HI), wAB, acc[1]);
    acc[2] = dot2h(permb(vB.y, vA.y, HSEL_LO), wAB, acc[2]);
    acc[3] = dot2h(permb(vB.y, vA.y, HSEL_HI), wAB, acc[3]);
    acc[4] = dot2h(permb(vB.z, vA.z, HSEL_LO), wAB, acc[4]);
    acc[5] = dot2h(permb(vB.z, vA.z, HSEL_HI), wAB, acc[5]);
    acc[6] = dot2h(permb(vB.w, vA.w, HSEL_LO), wAB, acc[6]);
    acc[7] = dot2h(permb(vB.w, vA.w, HSEL_HI), wAB, acc[7]);
  }
#pragma unroll
  for (int o = 16; o <= 32; o <<= 1) {
    den += __shfl_xor(den, o);
#pragma unroll
    for (int j = 0; j < 8; ++j) acc[j] += __shfl_xor(acc[j], o);
  }
  float4 bA = *(const float4*)&b1[lp * 8];
  float4 bB = *(const float4*)&b1[lp * 8 + 4];
  float bb[8] = {bA.x, bA.y, bA.z, bA.w, bB.x, bB.y, bB.z, bB.w};
  float inv = 1.f / (den + GEPS);
  float r[8];
#pragma unroll
  for (int j = 0; j < 8; ++j) {
    float v = acc[j] * inv + bb[j];
    r[j] = v > 0.f ? v : __expf(v) - 1.f;   // ELU
  }
  float4 wA = *(const float4*)&W2[lp * 16];
  float4 wB = *(const float4*)&W2[lp * 16 + 4];
  float4 wC = *(const float4*)&W2[lp * 16 + 8];
  float4 wD = *(const float4*)&W2[lp * 16 + 12];
  float p20 = r[0] * wA.x + r[1] * wA.z + r[2] * wB.x + r[3] * wB.z
            + r[4] * wC.x + r[5] * wC.z + r[6] * wD.x + r[7] * wD.z;
  float p21 = r[0] * wA.y + r[1] * wA.w + r[2] * wB.y + r[3] * wB.w
            + r[4] * wC.y + r[5] * wC.w + r[6] * wD.y + r[7] * wD.w;
#pragma unroll
  for (int o = 1; o <= 8; o <<= 1) { p20 += __shfl_xor(p20, o); p21 += __shfl_xor(p21, o); }
  if (lane == 0) {
    float4 v;
    v.x = p20; v.y = p21;
    v.z = p20 * as2[0] + p21 * as2[1];
    v.w = p20 * ad2[0] + p21 * ad2[1];
    nd[n] = v;
  }
}

// ---------- layer2 aggregation: 4 nodes/wave (16-lane granules) ----------
// Pad packets: ez=-1e30 -> exp() = 0, safe to process.
__global__ __launch_bounds__(256) void k_agg2(const int* __restrict__ rowptr,
                                              const float4* __restrict__ cpk,
                                              const float4* __restrict__ nd,
                                              const float* __restrict__ b2,
                                              float* __restrict__ out) {
  int wid = (int)((blockIdx.x * 256 + threadIdx.x) >> 6);
  int lane = threadIdx.x & 63;
  int g = lane >> 4, lp = lane & 15;
  int n = wid * 4 + g;
  if (n >= NN) return;
  int s0 = rowptr[n], s1 = rowptr[n + 1];
  float adn = nd[n].w;
  float den = 0.f, acc0 = 0.f, acc1 = 0.f;
  for (int i = s0 + lp; i < s1; i += 16) {
    float4 pk = cpk[i];
    int s = __float_as_int(pk.z);
    float4 ns = nd[s];
    float v = ns.z + adn + pk.y;
    v = v > 0.f ? v : NEG_SLOPE * v;
    float p = __expf(v);
    den += p;
    acc0 += p * ns.x;
    acc1 += p * ns.y;
  }
#pragma unroll
  for (int o = 1; o <= 8; o <<= 1) {
    den += __shfl_xor(den, o);
    acc0 += __shfl_xor(acc0, o);
    acc1 += __shfl_xor(acc1, o);
  }
  if (lp == 0) {
    float2 r;
    r.x = acc0 / (den + GEPS) + b2[0];
    r.y = acc1 / (den + GEPS) + b2[1];
    *(float2*)&out[n * 2] = r;
  }
}

extern "C" void kernel_launch(void* const* d_in, const int* in_sizes, int n_in,
                              void* d_out, int out_size, void* d_ws, size_t ws_size,
                              hipStream_t stream) {
  (void)in_sizes; (void)n_in; (void)out_size; (void)ws_size;
  const float* x   = (const float*)d_in[0];
  const int*   ei  = (const int*)d_in[1];
  const float* ef  = (const float*)d_in[2];
  const float* W1  = (const float*)d_in[3];
  const float* We1 = (const float*)d_in[4];
  const float* as1 = (const float*)d_in[5];
  const float* ad1 = (const float*)d_in[6];
  const float* ae1 = (const float*)d_in[7];
  const float* b1  = (const float*)d_in[8];
  const float* W2  = (const float*)d_in[9];
  const float* We2 = (const float*)d_in[10];
  const float* as2 = (const float*)d_in[11];
  const float* ad2 = (const float*)d_in[12];
  const float* ae2 = (const float*)d_in[13];
  const float* b2  = (const float*)d_in[14];
  float* out = (float*)d_out;

  char* w = (char*)d_ws;
  auto alloc = [&](size_t bytes) -> char* {
    char* p = w; w += (bytes + 255) & ~(size_t)255; return p;
  };
  unsigned short* h1b = (unsigned short*)alloc((size_t)NN * 128 * 2);  // 25.6 MB (f16)
  float*  a1s    = (float*)alloc((size_t)NN * 2 * 4);
  float*  a1d    = (float*)alloc((size_t)NN * 2 * 4);
  float4* nd     = (float4*)alloc((size_t)NN * 16);
  float*  q      = (float*)alloc(64);
  float4* pq     = (float4*)alloc(128 * 16);
  int*    deg    = (int*)alloc((size_t)NN * 4);
  int*    rowptr = (int*)alloc((size_t)(NN + 1) * 4);
  unsigned short* rank  = (unsigned short*)alloc((size_t)NE * 2);       // 3.2 MB
  unsigned short* off16 = (unsigned short*)alloc((size_t)HB * NN * 2);  // 6.4 MB
  int*    bsum   = (int*)alloc(128 * 4);
  float4* cpk    = (float4*)alloc(((size_t)NE + 8 * NN) * 16);  // padded CSR, 38.4 MB

  const int NB_SCAN = (NN + 1023) / 1024;                 // 98

  hipLaunchKernelGGL(k_prep, dim3(1), dim3(128), 0, stream,
                     We1, ae1, We2, ae2, W1, as1, ad1, q, pq);
  hipLaunchKernelGGL(k_gemm, dim3((NN + 127) / 128), dim3(512), 0, stream,
                     x, W1, pq, h1b, a1s, a1d);
  hipLaunchKernelGGL(k_hist, dim3(HB * HPASS), dim3(1024), 0, stream, ei, off16, rank);
  hipLaunchKernelGGL(k_sumdeg, dim3((NN + 255) / 256), dim3(256), 0, stream, off16, deg);
  hipLaunchKernelGGL(k_scan1, dim3(NB_SCAN), dim3(256), 0, stream, deg, bsum);
  hipLaunchKernelGGL(k_scan2, dim3(1), dim3(128), 0, stream, bsum, NB_SCAN);
  hipLaunchKernelGGL(k_scan3, dim3(NB_SCAN), dim3(256), 0, stream,
                     deg, bsum, a1s, a1d, rowptr, cpk);
  hipLaunchKernelGGL(k_scatter, dim3((NE / 4 + 255) / 256), dim3(256), 0, stream,
                     ei, ef, a1s, a1d, q, rowptr, rank, off16, cpk);
  hipLaunchKernelGGL(k_agg1, dim3((NN * 64 + 255) / 256), dim3(256), 0, stream,
                     h1b, rowptr, cpk, b1, W2, as2, ad2, nd);
  hipLaunchKernelGGL(k_agg2, dim3(((NN + 3) / 4 * 64 + 255) / 256), dim3(256), 0, stream,
                     rowptr, cpk, nd, b2, out);
}